// Round 9
// baseline (466.460 us; speedup 1.0000x reference)
//
#include <hip/hip_runtime.h>
#include <hip/hip_bf16.h>
#include <math.h>

#define D_MODEL 1024
#define D_HID   4096
#define NE      8
#define NTOK    4096
#define NSLOT   8192

typedef __attribute__((ext_vector_type(8))) short s8v;
typedef __attribute__((ext_vector_type(4))) float f32x4;

__device__ __forceinline__ short f2bf(float f) {
    unsigned u = __float_as_uint(f);
    unsigned r = (u + 0x7fffu + ((u >> 16) & 1u)) >> 16;
    return (short)r;
}

__device__ __forceinline__ void load_lds16(const short* g, short* l) {
    __builtin_amdgcn_global_load_lds(
        (const __attribute__((address_space(1))) void*)g,
        (__attribute__((address_space(3))) void*)l, 16, 0, 0);
}

// exact-GELU via A&S 7.1.26 erf (|eps| < 1.5e-7), branchless
__device__ __forceinline__ float gelu_f(float v) {
    float z  = v * 0.70710678118f;
    float az = fabsf(z);
    float t  = __builtin_amdgcn_rcpf(fmaf(0.3275911f, az, 1.0f));
    float p  = fmaf(1.061405429f, t, -1.453152027f);
    p = fmaf(p, t, 1.421413741f);
    p = fmaf(p, t, -0.284496736f);
    p = fmaf(p, t, 0.254829592f);
    p = p * t;
    float e  = __expf(-az * az);
    float er = fmaf(-p, e, 1.0f);          // erf(|z|)
    er = copysignf(er, z);
    return v * fmaf(0.5f, er, 0.5f);
}

// ---------------- conversion kernels ----------------

__global__ void k_cvt_x(const float* __restrict__ x, short* __restrict__ xb) {
    int i = blockIdx.x * blockDim.x + threadIdx.x;
    size_t base = (size_t)i * 4;
    float4 v = *(const float4*)(x + base);
    short4 o;
    o.x = f2bf(v.x); o.y = f2bf(v.y); o.z = f2bf(v.z); o.w = f2bf(v.w);
    *(short4*)(xb + base) = o;
}

// both weight transposes in ONE launch: z<8 -> w1 expert z; z>=8 -> w2 expert z-8.
// in: [R][C] fp32 -> out: [C][R] bf16 (float4 loads, short4 stores)
__global__ void k_transpose_cvt2(const float* __restrict__ w1, const float* __restrict__ w2,
                                 short* __restrict__ w1t, short* __restrict__ w2t) {
    __shared__ float tile[64][65];
    int z = blockIdx.z;
    int R, C;
    const float* inp;
    short* outp;
    int tIdx = blockIdx.y * 64 + blockIdx.x;   // 0..1023 tile id
    if (z < 8) {
        R = D_MODEL; C = D_HID;
        inp  = w1  + (size_t)z * R * C;
        outp = w1t + (size_t)z * R * C;
    } else {
        R = D_HID; C = D_MODEL;
        inp  = w2  + (size_t)(z - 8) * R * C;
        outp = w2t + (size_t)(z - 8) * R * C;
    }
    int tilesC = C >> 6;
    int c0 = (tIdx % tilesC) * 64;
    int r0 = (tIdx / tilesC) * 64;
    int t = threadIdx.x;
    #pragma unroll
    for (int p = 0; p < 4; p++) {
        int idx = p * 256 + t;
        int r = idx >> 4;
        int c4 = (idx & 15) * 4;
        float4 v = *(const float4*)(inp + (size_t)(r0 + r) * C + c0 + c4);
        tile[r][c4 + 0] = v.x; tile[r][c4 + 1] = v.y;
        tile[r][c4 + 2] = v.z; tile[r][c4 + 3] = v.w;
    }
    __syncthreads();
    #pragma unroll
    for (int p = 0; p < 4; p++) {
        int idx = p * 256 + t;
        int cc = idx >> 4;
        int rg = (idx & 15) * 4;
        short4 v;
        v.x = f2bf(tile[rg + 0][cc]);
        v.y = f2bf(tile[rg + 1][cc]);
        v.z = f2bf(tile[rg + 2][cc]);
        v.w = f2bf(tile[rg + 3][cc]);
        *(short4*)(outp + (size_t)(c0 + cc) * R + r0 + rg) = v;
    }
}

// ---------------- router ----------------

__global__ void k_router(const float* __restrict__ x, const float* __restrict__ gw,
                         int* __restrict__ tki, float* __restrict__ tkw) {
    int n = blockIdx.x;
    int lane = threadIdx.x;
    const float* xr = x + (size_t)n * D_MODEL;
    float xs[16];
    #pragma unroll
    for (int j = 0; j < 16; j++) xs[j] = xr[lane + 64 * j];
    float l[8];
    #pragma unroll
    for (int e = 0; e < 8; e++) {
        const float* g = gw + e * D_MODEL;
        float a = 0.f;
        #pragma unroll
        for (int j = 0; j < 16; j++) a += xs[j] * g[lane + 64 * j];
        #pragma unroll
        for (int s = 32; s > 0; s >>= 1) a += __shfl_xor(a, s);
        l[e] = a;
    }
    if (lane == 0) {
        float bv = -1e30f, sv = -1e30f; int bi = 0, si = 0;
        #pragma unroll
        for (int e = 0; e < 8; e++) {
            float v = l[e];
            if (v > bv) { sv = bv; si = bi; bv = v; bi = e; }
            else if (v > sv) { sv = v; si = e; }
        }
        float w0 = 1.f / (1.f + expf(sv - bv));
        tki[n * 2] = bi; tki[n * 2 + 1] = si;
        tkw[n * 2] = w0; tkw[n * 2 + 1] = 1.f - w0;
    }
}

// ---------------- bucketing ----------------

__global__ void k_count(const int* __restrict__ tki, int* __restrict__ cnt) {
    int n = blockIdx.x * blockDim.x + threadIdx.x;
    if (n < NTOK) {
        atomicAdd(&cnt[tki[n * 2]], 1);
        atomicAdd(&cnt[tki[n * 2 + 1]], 1);
    }
}

__global__ void k_scan(const int* __restrict__ cnt, int* __restrict__ offs) {
    if (threadIdx.x == 0) {
        int a = 0;
        for (int e = 0; e < NE; e++) { offs[e] = a; a += cnt[e]; }
        offs[NE] = a;
    }
}

__global__ void k_fill(const int* __restrict__ tki, const float* __restrict__ tkw,
                       const int* __restrict__ offs, int* __restrict__ fill,
                       int* __restrict__ list, float* __restrict__ wl) {
    int n = blockIdx.x * blockDim.x + threadIdx.x;
    if (n < NTOK) {
        #pragma unroll
        for (int k = 0; k < 2; k++) {
            int e = tki[n * 2 + k];
            int p = offs[e] + atomicAdd(&fill[e], 1);
            list[p] = n;
            wl[p] = tkw[n * 2 + k];
        }
    }
}

// ---------------- GEMM machinery (128x128 tile, BK=64, 4 waves) ----------------
// Round-6-verified structure: LDS [128][64] bf16 tiles, XOR swizzle (phys 16B
// slot s of row r holds logical chunk s^(r&7); linear LDS dest for
// global_load_lds + pre-swizzled global source; same XOR on ds_read).
// Counted-vmcnt pipeline: STAGE(next)'s 8 loads stay in flight during
// COMPUTE(cur); vmcnt(8) waits only for cur's loads; raw s_barrier.
// 64KB LDS -> 2 blocks/CU for co-resident overlap.

#define STAGE_PAIR(ABASE, BBASE) \
    { _Pragma("unroll") \
      for (int c = 0; c < 4; c++) { \
          load_lds16(aS[c], (ABASE) + ldsD[c]); \
          load_lds16(bS[c], (BBASE) + ldsD[c]); \
          aS[c] += 64; bS[c] += 64; \
      } }

#define COMPUTE_STEP(ABASE, BBASE) \
    { _Pragma("unroll") \
      for (int kk2 = 0; kk2 < 2; kk2++) { \
          s8v a[4], b[4]; \
          _Pragma("unroll") \
          for (int i = 0; i < 4; i++) { \
              a[i] = *(const s8v*)((ABASE) + aO[i][kk2]); \
              b[i] = *(const s8v*)((BBASE) + bO[i][kk2]); \
          } \
          _Pragma("unroll") \
          for (int i = 0; i < 4; i++) \
              _Pragma("unroll") \
              for (int j = 0; j < 4; j++) \
                  acc[i][j] = __builtin_amdgcn_mfma_f32_16x16x32_bf16(a[i], b[j], acc[i][j], 0, 0, 0); \
      } }

#define PIPE_WAIT8 \
    asm volatile("s_waitcnt vmcnt(8)" ::: "memory"); \
    __builtin_amdgcn_s_barrier(); \
    __builtin_amdgcn_sched_barrier(0); \
    __builtin_amdgcn_s_setprio(1);

#define PIPE_WAIT0 \
    asm volatile("s_waitcnt vmcnt(0)" ::: "memory"); \
    __builtin_amdgcn_s_barrier(); \
    __builtin_amdgcn_sched_barrier(0); \
    __builtin_amdgcn_s_setprio(1);

#define PIPE_POST \
    __builtin_amdgcn_s_setprio(0); \
    asm volatile("" ::: "memory"); \
    __builtin_amdgcn_s_barrier();

#define GEMM_PIPE_LOOP(KDIM) \
    STAGE_PAIR(As0, Bs0); \
    for (int k0 = 0; k0 < (KDIM) - 128; k0 += 128) { \
        STAGE_PAIR(As1, Bs1); PIPE_WAIT8 COMPUTE_STEP(As0, Bs0) PIPE_POST \
        STAGE_PAIR(As0, Bs0); PIPE_WAIT8 COMPUTE_STEP(As1, Bs1) PIPE_POST \
    } \
    STAGE_PAIR(As1, Bs1); PIPE_WAIT8 COMPUTE_STEP(As0, Bs0) PIPE_POST \
    PIPE_WAIT0 COMPUTE_STEP(As1, Bs1) \
    __builtin_amdgcn_s_setprio(0);

#define GEMM_FRAG_SETUP \
    int tid = threadIdx.x; \
    int lane = tid & 63; \
    int wid = tid >> 6; \
    int wm = wid >> 1, wn = wid & 1; \
    f32x4 acc[4][4] = {}; \
    int ldsD[4]; \
    _Pragma("unroll") \
    for (int c = 0; c < 4; c++) ldsD[c] = (c * 256 + tid) * 8; \
    int aO[4][2], bO[4][2]; \
    _Pragma("unroll") \
    for (int i = 0; i < 4; i++) \
        _Pragma("unroll") \
        for (int k = 0; k < 2; k++) { \
            int l = k * 4 + (lane >> 4); \
            int R = wm * 64 + i * 16 + (lane & 15); \
            aO[i][k] = R * 64 + ((l ^ (R & 7)) * 8); \
            R = wn * 64 + i * 16 + (lane & 15); \
            bO[i][k] = R * 64 + ((l ^ (R & 7)) * 8); \
        }

// ---------------- GEMM 1: h = gelu(X_gather @ W1 + b1), bf16 out ----------------
// Round-6-MEASURED-best map (141 vs 153 us natural): expert = XCD = id&7;
// w=(id&7)*1024+id>>3; n0=(w&31)*128, m0=((w>>5)&31)*128.

__global__ __launch_bounds__(256, 2) void k_gemm1(
    const short* __restrict__ xb,      // [NTOK][D_MODEL] bf16
    const short* __restrict__ w1t,     // [E][D_HID][D_MODEL] bf16
    const float* __restrict__ b1,
    const int* __restrict__ offs,
    const int* __restrict__ list,
    short* __restrict__ hbuf)          // [NSLOT][D_HID] bf16
{
    int id = blockIdx.x;
    int w = (id & 7) * 1024 + (id >> 3);
    int e = w >> 10;
    int o0 = offs[e];
    int nE = offs[e + 1] - o0;
    int m0 = ((w >> 5) & 31) * 128;
    if (m0 >= nE) return;
    int n0 = (w & 31) * 128;

    __shared__ short As0[128 * 64], Bs0[128 * 64];
    __shared__ short As1[128 * 64], Bs1[128 * 64];

    GEMM_FRAG_SETUP

    const short* aS[4]; const short* bS[4];
    #pragma unroll
    for (int c = 0; c < 4; c++) {
        int i = c * 256 + tid;
        int rowT = i >> 3, s = i & 7;
        int ch = s ^ (rowT & 7);                 // pre-swizzled source chunk
        int r = m0 + rowT; if (r > nE - 1) r = nE - 1;
        int tok = list[o0 + r];
        aS[c] = xb + (size_t)tok * D_MODEL + ch * 8;
        bS[c] = w1t + ((size_t)e * D_HID + n0 + rowT) * D_MODEL + ch * 8;
    }

    GEMM_PIPE_LOOP(D_MODEL)

    int rBase = m0 + wm * 64 + (lane >> 4) * 4;
    int cBase = n0 + wn * 64 + (lane & 15);
    #pragma unroll
    for (int i = 0; i < 4; i++) {
        #pragma unroll
        for (int j = 0; j < 4; j++) {
            int cc = cBase + j * 16;
            float bias = b1[e * D_HID + cc];
            #pragma unroll
            for (int rg = 0; rg < 4; rg++) {
                int rr = rBase + i * 16 + rg;
                if (rr < nE) {
                    float v = acc[i][j][rg] + bias;
                    hbuf[(size_t)(o0 + rr) * D_HID + cc] = f2bf(gelu_f(v));
                }
            }
        }
    }
}

// ---------------- GEMM 2: out[tok] += w_slot*(H @ W2 + b2), fused combine ----------------
// Round-6-verified map (FETCH 80MB): w=(id%8)*256+id/8 -> XCD owns one expert;
// bx=w&7, by=(w>>3)&31, e=w>>8. Epilogue: fp32 atomicAdd into out[token];
// each element receives exactly 2 commutative contributions -> deterministic.

__global__ __launch_bounds__(256, 2) void k_gemm2(
    const short* __restrict__ hbuf,    // [NSLOT][D_HID] bf16
    const short* __restrict__ w2t,     // [E][D_MODEL][D_HID] bf16
    const float* __restrict__ b2,
    const int* __restrict__ offs,
    const float* __restrict__ wl,
    const int* __restrict__ list,
    float* __restrict__ out)           // [NTOK][D_MODEL] fp32 (atomic)
{
    int id = blockIdx.x;
    int w = (id & 7) * 256 + (id >> 3);
    int e = w >> 8;
    int o0 = offs[e];
    int nE = offs[e + 1] - o0;
    int m0 = ((w >> 3) & 31) * 128;
    if (m0 >= nE) return;
    int n0 = (w & 7) * 128;

    __shared__ short As0[128 * 64], Bs0[128 * 64];
    __shared__ short As1[128 * 64], Bs1[128 * 64];

    GEMM_FRAG_SETUP

    const short* aS[4]; const short* bS[4];
    #pragma unroll
    for (int c = 0; c < 4; c++) {
        int i = c * 256 + tid;
        int rowT = i >> 3, s = i & 7;
        int ch = s ^ (rowT & 7);
        int r = m0 + rowT; if (r > nE - 1) r = nE - 1;
        aS[c] = hbuf + (size_t)(o0 + r) * D_HID + ch * 8;
        bS[c] = w2t + ((size_t)e * D_MODEL + n0 + rowT) * D_HID + ch * 8;
    }

    GEMM_PIPE_LOOP(D_HID)

    int rBase = m0 + wm * 64 + (lane >> 4) * 4;
    int cBase = n0 + wn * 64 + (lane & 15);
    #pragma unroll
    for (int i = 0; i < 4; i++) {
        #pragma unroll
        for (int j = 0; j < 4; j++) {
            int cc = cBase + j * 16;
            float bias = b2[e * D_MODEL + cc];
            #pragma unroll
            for (int rg = 0; rg < 4; rg++) {
                int rr = rBase + i * 16 + rg;
                if (rr < nE) {
                    int slot = o0 + rr;
                    float wgt = wl[slot];
                    int tok = list[slot];
                    atomicAdd(&out[(size_t)tok * D_MODEL + cc], wgt * (acc[i][j][rg] + bias));
                }
            }
        }
    }
}

// ---------------- launch ----------------

extern "C" void kernel_launch(void* const* d_in, const int* in_sizes, int n_in,
                              void* d_out, int out_size, void* d_ws, size_t ws_size,
                              hipStream_t stream) {
    const float* x  = (const float*)d_in[0];
    const float* gw = (const float*)d_in[1];
    const float* w1 = (const float*)d_in[2];
    const float* b1 = (const float*)d_in[3];
    const float* w2 = (const float*)d_in[4];
    const float* b2 = (const float*)d_in[5];
    float* out = (float*)d_out;

    char* ws = (char*)d_ws;
    size_t off = 0;
    auto alloc = [&](size_t bytes) -> void* {
        void* p = ws + off;
        off += (bytes + 255) & ~(size_t)255;
        return p;
    };
    int*   meta    = (int*)alloc(256);
    int*   cnt     = meta;
    int*   fill    = meta + 8;
    int*   offs    = meta + 16;
    int*   tki     = (int*)alloc((size_t)NTOK * 2 * 4);
    float* tkw     = (float*)alloc((size_t)NTOK * 2 * 4);
    int*   list    = (int*)alloc((size_t)NSLOT * 4);
    float* wl      = (float*)alloc((size_t)NSLOT * 4);
    short* xb      = (short*)alloc((size_t)NTOK * D_MODEL * 2);
    short* w1t     = (short*)alloc((size_t)NE * D_HID * D_MODEL * 2);
    short* w2t     = (short*)alloc((size_t)NE * D_MODEL * D_HID * 2);
    short* hbuf    = (short*)alloc((size_t)NSLOT * D_HID * 2);

    hipMemsetAsync(meta, 0, 256, stream);
    hipMemsetAsync(out, 0, (size_t)NTOK * D_MODEL * 4, stream);
    k_cvt_x<<<dim3(NTOK * D_MODEL / (4 * 256)), 256, 0, stream>>>(x, xb);
    k_transpose_cvt2<<<dim3(64, 16, 16), 256, 0, stream>>>(w1, w2, w1t, w2t);
    k_router<<<dim3(NTOK), 64, 0, stream>>>(x, gw, tki, tkw);
    k_count<<<dim3(NTOK / 256), 256, 0, stream>>>(tki, cnt);
    k_scan<<<dim3(1), 64, 0, stream>>>(cnt, offs);
    k_fill<<<dim3(NTOK / 256), 256, 0, stream>>>(tki, tkw, offs, fill, list, wl);
    k_gemm1<<<dim3(8192), 256, 0, stream>>>(xb, w1t, b1, offs, list, hbuf);
    k_gemm2<<<dim3(2048), 256, 0, stream>>>(hbuf, w2t, b2, offs, wl, list, out);
}

// Round 10
// 459.796 us; speedup vs baseline: 1.0145x; 1.0145x over previous
//
#include <hip/hip_runtime.h>
#include <hip/hip_bf16.h>
#include <math.h>

#define D_MODEL 1024
#define D_HID   4096
#define NE      8
#define NTOK    4096
#define NSLOT   8192

typedef __attribute__((ext_vector_type(8))) short s8v;
typedef __attribute__((ext_vector_type(4))) float f32x4;

__device__ __forceinline__ short f2bf(float f) {
    unsigned u = __float_as_uint(f);
    unsigned r = (u + 0x7fffu + ((u >> 16) & 1u)) >> 16;
    return (short)r;
}

__device__ __forceinline__ void load_lds16(const short* g, short* l) {
    __builtin_amdgcn_global_load_lds(
        (const __attribute__((address_space(1))) void*)g,
        (__attribute__((address_space(3))) void*)l, 16, 0, 0);
}

// exact-GELU via A&S 7.1.26 erf (|eps| < 1.5e-7), branchless
__device__ __forceinline__ float gelu_f(float v) {
    float z  = v * 0.70710678118f;
    float az = fabsf(z);
    float t  = __builtin_amdgcn_rcpf(fmaf(0.3275911f, az, 1.0f));
    float p  = fmaf(1.061405429f, t, -1.453152027f);
    p = fmaf(p, t, 1.421413741f);
    p = fmaf(p, t, -0.284496736f);
    p = fmaf(p, t, 0.254829592f);
    p = p * t;
    float e  = __expf(-az * az);
    float er = fmaf(-p, e, 1.0f);          // erf(|z|)
    er = copysignf(er, z);
    return v * fmaf(0.5f, er, 0.5f);
}

// ---------------- conversion kernels ----------------

__global__ void k_cvt_x(const float* __restrict__ x, short* __restrict__ xb) {
    int i = blockIdx.x * blockDim.x + threadIdx.x;
    size_t base = (size_t)i * 4;
    float4 v = *(const float4*)(x + base);
    short4 o;
    o.x = f2bf(v.x); o.y = f2bf(v.y); o.z = f2bf(v.z); o.w = f2bf(v.w);
    *(short4*)(xb + base) = o;
}

// both weight transposes in ONE launch: z<8 -> w1 expert z; z>=8 -> w2 expert z-8.
__global__ void k_transpose_cvt2(const float* __restrict__ w1, const float* __restrict__ w2,
                                 short* __restrict__ w1t, short* __restrict__ w2t) {
    __shared__ float tile[64][65];
    int z = blockIdx.z;
    int R, C;
    const float* inp;
    short* outp;
    int tIdx = blockIdx.y * 64 + blockIdx.x;
    if (z < 8) {
        R = D_MODEL; C = D_HID;
        inp  = w1  + (size_t)z * R * C;
        outp = w1t + (size_t)z * R * C;
    } else {
        R = D_HID; C = D_MODEL;
        inp  = w2  + (size_t)(z - 8) * R * C;
        outp = w2t + (size_t)(z - 8) * R * C;
    }
    int tilesC = C >> 6;
    int c0 = (tIdx % tilesC) * 64;
    int r0 = (tIdx / tilesC) * 64;
    int t = threadIdx.x;
    #pragma unroll
    for (int p = 0; p < 4; p++) {
        int idx = p * 256 + t;
        int r = idx >> 4;
        int c4 = (idx & 15) * 4;
        float4 v = *(const float4*)(inp + (size_t)(r0 + r) * C + c0 + c4);
        tile[r][c4 + 0] = v.x; tile[r][c4 + 1] = v.y;
        tile[r][c4 + 2] = v.z; tile[r][c4 + 3] = v.w;
    }
    __syncthreads();
    #pragma unroll
    for (int p = 0; p < 4; p++) {
        int idx = p * 256 + t;
        int cc = idx >> 4;
        int rg = (idx & 15) * 4;
        short4 v;
        v.x = f2bf(tile[rg + 0][cc]);
        v.y = f2bf(tile[rg + 1][cc]);
        v.z = f2bf(tile[rg + 2][cc]);
        v.w = f2bf(tile[rg + 3][cc]);
        *(short4*)(outp + (size_t)(c0 + cc) * R + r0 + rg) = v;
    }
}

// ---------------- router ----------------

__global__ void k_router(const float* __restrict__ x, const float* __restrict__ gw,
                         int* __restrict__ tki, float* __restrict__ tkw) {
    int n = blockIdx.x;
    int lane = threadIdx.x;
    const float* xr = x + (size_t)n * D_MODEL;
    float xs[16];
    #pragma unroll
    for (int j = 0; j < 16; j++) xs[j] = xr[lane + 64 * j];
    float l[8];
    #pragma unroll
    for (int e = 0; e < 8; e++) {
        const float* g = gw + e * D_MODEL;
        float a = 0.f;
        #pragma unroll
        for (int j = 0; j < 16; j++) a += xs[j] * g[lane + 64 * j];
        #pragma unroll
        for (int s = 32; s > 0; s >>= 1) a += __shfl_xor(a, s);
        l[e] = a;
    }
    if (lane == 0) {
        float bv = -1e30f, sv = -1e30f; int bi = 0, si = 0;
        #pragma unroll
        for (int e = 0; e < 8; e++) {
            float v = l[e];
            if (v > bv) { sv = bv; si = bi; bv = v; bi = e; }
            else if (v > sv) { sv = v; si = e; }
        }
        float w0 = 1.f / (1.f + expf(sv - bv));
        tki[n * 2] = bi; tki[n * 2 + 1] = si;
        tkw[n * 2] = w0; tkw[n * 2 + 1] = 1.f - w0;
    }
}

// ---------------- bucketing ----------------

__global__ void k_count(const int* __restrict__ tki, int* __restrict__ cnt) {
    int n = blockIdx.x * blockDim.x + threadIdx.x;
    if (n < NTOK) {
        atomicAdd(&cnt[tki[n * 2]], 1);
        atomicAdd(&cnt[tki[n * 2 + 1]], 1);
    }
}

__global__ void k_scan(const int* __restrict__ cnt, int* __restrict__ offs) {
    if (threadIdx.x == 0) {
        int a = 0;
        for (int e = 0; e < NE; e++) { offs[e] = a; a += cnt[e]; }
        offs[NE] = a;
    }
}

__global__ void k_fill(const int* __restrict__ tki, const float* __restrict__ tkw,
                       const int* __restrict__ offs, int* __restrict__ fill,
                       int* __restrict__ list, float* __restrict__ wl,
                       int* __restrict__ slot_of) {
    int n = blockIdx.x * blockDim.x + threadIdx.x;
    if (n < NTOK) {
        #pragma unroll
        for (int k = 0; k < 2; k++) {
            int e = tki[n * 2 + k];
            int p = offs[e] + atomicAdd(&fill[e], 1);
            list[p] = n;
            wl[p] = tkw[n * 2 + k];
            slot_of[n * 2 + k] = p;
        }
    }
}

// ---------------- GEMM machinery ----------------
// 256-wide M tiles, BK=64, 512 threads / 8 waves (2M x 4N), counted-vmcnt
// 2-deep pipeline (round-6-verified race structure), XOR swizzle
// (round-3-verified: phys 16B slot s of row r holds logical chunk s^(r&7);
// linear LDS dest for global_load_lds + pre-swizzled global source; same XOR
// on ds_read; all frag row strides are 0 mod 8 so R&7 == lane&7).

#define PIPE_WAIT(NSTR) \
    asm volatile("s_waitcnt vmcnt(" NSTR ")" ::: "memory"); \
    __builtin_amdgcn_s_barrier(); \
    __builtin_amdgcn_sched_barrier(0); \
    __builtin_amdgcn_s_setprio(1);

#define PIPE_POST \
    __builtin_amdgcn_s_setprio(0); \
    asm volatile("" ::: "memory"); \
    __builtin_amdgcn_s_barrier();

#define GEMM_PIPE_LOOP(KDIM, STAGE, COMPUTE, NSTR) \
    STAGE(As0, Bs0); \
    for (int k0 = 0; k0 < (KDIM) - 128; k0 += 128) { \
        STAGE(As1, Bs1); PIPE_WAIT(NSTR) COMPUTE(As0, Bs0) PIPE_POST \
        STAGE(As0, Bs0); PIPE_WAIT(NSTR) COMPUTE(As1, Bs1) PIPE_POST \
    } \
    STAGE(As1, Bs1); PIPE_WAIT(NSTR) COMPUTE(As0, Bs0) PIPE_POST \
    PIPE_WAIT("0") COMPUTE(As1, Bs1) \
    __builtin_amdgcn_s_setprio(0);

// ---------------- GEMM 1: 256x256, h = gelu(X_gather @ W1 + b1) ----------------

#define STAGE1(ABASE, BBASE) \
    { _Pragma("unroll") \
      for (int c = 0; c < 4; c++) { load_lds16(aS[c], (ABASE) + ldsDa[c]); aS[c] += 64; } \
      _Pragma("unroll") \
      for (int c = 0; c < 4; c++) { load_lds16(bS[c], (BBASE) + ldsDb[c]); bS[c] += 64; } }

#define COMPUTE1(ABASE, BBASE) \
    { _Pragma("unroll") \
      for (int kk = 0; kk < 2; kk++) { \
          s8v a[8], b[4]; \
          _Pragma("unroll") \
          for (int i = 0; i < 8; i++) a[i] = *(const s8v*)((ABASE) + aB[kk] + i * 1024); \
          _Pragma("unroll") \
          for (int j = 0; j < 4; j++) b[j] = *(const s8v*)((BBASE) + bB[kk] + j * 1024); \
          _Pragma("unroll") \
          for (int i = 0; i < 8; i++) \
              _Pragma("unroll") \
              for (int j = 0; j < 4; j++) \
                  acc[i][j] = __builtin_amdgcn_mfma_f32_16x16x32_bf16(a[i], b[j], acc[i][j], 0, 0, 0); \
      } }

// grid 2048 1D; expert-per-XCD (round-6-measured-best family):
// w=(id&7)*256+id>>3; e=w>>8; m0=((w>>4)&15)*256; n0=(w&15)*256.
__global__ __launch_bounds__(512, 1) void k_gemm1(
    const short* __restrict__ xb,      // [NTOK][D_MODEL] bf16
    const short* __restrict__ w1t,     // [E][D_HID][D_MODEL] bf16
    const float* __restrict__ b1,
    const int* __restrict__ offs,
    const int* __restrict__ list,
    short* __restrict__ hbuf)          // [NSLOT][D_HID] bf16
{
    int id = blockIdx.x;
    int w = (id & 7) * 256 + (id >> 3);
    int e = w >> 8;
    int o0 = offs[e];
    int nE = offs[e + 1] - o0;
    int m0 = ((w >> 4) & 15) * 256;
    if (m0 >= nE) return;
    int n0 = (w & 15) * 256;

    __shared__ short As0[256 * 64], Bs0[256 * 64];
    __shared__ short As1[256 * 64], Bs1[256 * 64];

    int tid = threadIdx.x;
    int lane = tid & 63;
    int wid = tid >> 6;
    int wm = wid >> 2, wn = wid & 3;

    f32x4 acc[8][4] = {};

    const short* aS[4]; const short* bS[4];
    int ldsDa[4], ldsDb[4];
    #pragma unroll
    for (int c = 0; c < 4; c++) {
        int i = c * 512 + tid;                   // 0..2047
        int rowT = i >> 3, s = i & 7;
        int ch = s ^ (rowT & 7);                 // pre-swizzled source chunk
        int r = m0 + rowT; if (r > nE - 1) r = nE - 1;
        int tok = list[o0 + r];
        aS[c] = xb + (size_t)tok * D_MODEL + ch * 8;
        bS[c] = w1t + ((size_t)e * D_HID + n0 + rowT) * D_MODEL + ch * 8;
        ldsDa[c] = i * 8;
        ldsDb[c] = i * 8;
    }

    int aB[2], bB[2];
    #pragma unroll
    for (int kk = 0; kk < 2; kk++) {
        int l = kk * 4 + (lane >> 4);
        int xorm = (l ^ (lane & 7)) * 8;
        aB[kk] = (wm * 128 + (lane & 15)) * 64 + xorm;
        bB[kk] = (wn * 64  + (lane & 15)) * 64 + xorm;
    }

    GEMM_PIPE_LOOP(D_MODEL, STAGE1, COMPUTE1, "8")

    int rBase = m0 + wm * 128 + (lane >> 4) * 4;
    int cBase = n0 + wn * 64 + (lane & 15);
    #pragma unroll
    for (int i = 0; i < 8; i++) {
        #pragma unroll
        for (int j = 0; j < 4; j++) {
            int cc = cBase + j * 16;
            float bias = b1[e * D_HID + cc];
            #pragma unroll
            for (int rg = 0; rg < 4; rg++) {
                int rr = rBase + i * 16 + rg;
                if (rr < nE) {
                    float v = acc[i][j][rg] + bias;
                    hbuf[(size_t)(o0 + rr) * D_HID + cc] = f2bf(gelu_f(v));
                }
            }
        }
    }
}

// ---------------- GEMM 2: 256x128, y = w_slot*(H @ W2 + b2) ----------------

#define STAGE2(ABASE, BBASE) \
    { _Pragma("unroll") \
      for (int c = 0; c < 4; c++) { load_lds16(aS[c], (ABASE) + ldsDa[c]); aS[c] += 64; } \
      _Pragma("unroll") \
      for (int c = 0; c < 2; c++) { load_lds16(bS[c], (BBASE) + ldsDb[c]); bS[c] += 64; } }

#define COMPUTE2(ABASE, BBASE) \
    { _Pragma("unroll") \
      for (int kk = 0; kk < 2; kk++) { \
          s8v a[8], b[2]; \
          _Pragma("unroll") \
          for (int i = 0; i < 8; i++) a[i] = *(const s8v*)((ABASE) + aB[kk] + i * 1024); \
          _Pragma("unroll") \
          for (int j = 0; j < 2; j++) b[j] = *(const s8v*)((BBASE) + bB[kk] + j * 1024); \
          _Pragma("unroll") \
          for (int i = 0; i < 8; i++) \
              _Pragma("unroll") \
              for (int j = 0; j < 2; j++) \
                  acc[i][j] = __builtin_amdgcn_mfma_f32_16x16x32_bf16(a[i], b[j], acc[i][j], 0, 0, 0); \
      } }

// grid 1024 1D; w=(id&7)*128+id>>3; e=w>>7; m0=((w>>3)&15)*256; n0=(w&7)*128.
__global__ __launch_bounds__(512, 1) void k_gemm2(
    const short* __restrict__ hbuf,    // [NSLOT][D_HID] bf16
    const short* __restrict__ w2t,     // [E][D_MODEL][D_HID] bf16
    const float* __restrict__ b2,
    const int* __restrict__ offs,
    const float* __restrict__ wl,
    float* __restrict__ ybuf)          // [NSLOT][D_MODEL] fp32
{
    int id = blockIdx.x;
    int w = (id & 7) * 128 + (id >> 3);
    int e = w >> 7;
    int o0 = offs[e];
    int nE = offs[e + 1] - o0;
    int m0 = ((w >> 3) & 15) * 256;
    if (m0 >= nE) return;
    int n0 = (w & 7) * 128;

    __shared__ short As0[256 * 64], Bs0[128 * 64];
    __shared__ short As1[256 * 64], Bs1[128 * 64];

    int tid = threadIdx.x;
    int lane = tid & 63;
    int wid = tid >> 6;
    int wm = wid >> 2, wn = wid & 3;

    f32x4 acc[8][2] = {};

    const short* aS[4]; const short* bS[2];
    int ldsDa[4], ldsDb[2];
    #pragma unroll
    for (int c = 0; c < 4; c++) {
        int i = c * 512 + tid;
        int rowT = i >> 3, s = i & 7;
        int ch = s ^ (rowT & 7);
        int r = m0 + rowT; if (r > nE - 1) r = nE - 1;
        aS[c] = hbuf + (size_t)(o0 + r) * D_HID + ch * 8;
        ldsDa[c] = i * 8;
    }
    #pragma unroll
    for (int c = 0; c < 2; c++) {
        int i = c * 512 + tid;                   // 0..1023
        int rowT = i >> 3, s = i & 7;
        int ch = s ^ (rowT & 7);
        bS[c] = w2t + ((size_t)e * D_MODEL + n0 + rowT) * D_HID + ch * 8;
        ldsDb[c] = i * 8;
    }

    int aB[2], bB[2];
    #pragma unroll
    for (int kk = 0; kk < 2; kk++) {
        int l = kk * 4 + (lane >> 4);
        int xorm = (l ^ (lane & 7)) * 8;
        aB[kk] = (wm * 128 + (lane & 15)) * 64 + xorm;
        bB[kk] = (wn * 32  + (lane & 15)) * 64 + xorm;
    }

    GEMM_PIPE_LOOP(D_HID, STAGE2, COMPUTE2, "6")

    int rBase = m0 + wm * 128 + (lane >> 4) * 4;
    int cBase = n0 + wn * 32 + (lane & 15);
    #pragma unroll
    for (int i = 0; i < 8; i++) {
        #pragma unroll
        for (int j = 0; j < 2; j++) {
            int cc = cBase + j * 16;
            float bias = b2[e * D_MODEL + cc];
            #pragma unroll
            for (int rg = 0; rg < 4; rg++) {
                int rr = rBase + i * 16 + rg;
                if (rr < nE) {
                    int slot = o0 + rr;
                    float wgt = wl[slot];
                    ybuf[(size_t)slot * D_MODEL + cc] = wgt * (acc[i][j][rg] + bias);
                }
            }
        }
    }
}

// ---------------- combine ----------------

__global__ void k_combine(const float* __restrict__ ybuf, const int* __restrict__ slot_of,
                          float* __restrict__ out) {
    int n = blockIdx.x;
    int s0 = slot_of[n * 2], s1 = slot_of[n * 2 + 1];
    int t = threadIdx.x;
    float4 a = *(const float4*)(ybuf + (size_t)s0 * D_MODEL + t * 4);
    float4 b = *(const float4*)(ybuf + (size_t)s1 * D_MODEL + t * 4);
    float4 o;
    o.x = a.x + b.x; o.y = a.y + b.y; o.z = a.z + b.z; o.w = a.w + b.w;
    *(float4*)(out + (size_t)n * D_MODEL + t * 4) = o;
}

// ---------------- launch ----------------

extern "C" void kernel_launch(void* const* d_in, const int* in_sizes, int n_in,
                              void* d_out, int out_size, void* d_ws, size_t ws_size,
                              hipStream_t stream) {
    const float* x  = (const float*)d_in[0];
    const float* gw = (const float*)d_in[1];
    const float* w1 = (const float*)d_in[2];
    const float* b1 = (const float*)d_in[3];
    const float* w2 = (const float*)d_in[4];
    const float* b2 = (const float*)d_in[5];
    float* out = (float*)d_out;

    char* ws = (char*)d_ws;
    size_t off = 0;
    auto alloc = [&](size_t bytes) -> void* {
        void* p = ws + off;
        off += (bytes + 255) & ~(size_t)255;
        return p;
    };
    int*   meta    = (int*)alloc(256);
    int*   cnt     = meta;
    int*   fill    = meta + 8;
    int*   offs    = meta + 16;
    int*   tki     = (int*)alloc((size_t)NTOK * 2 * 4);
    float* tkw     = (float*)alloc((size_t)NTOK * 2 * 4);
    int*   list    = (int*)alloc((size_t)NSLOT * 4);
    float* wl      = (float*)alloc((size_t)NSLOT * 4);
    int*   slot_of = (int*)alloc((size_t)NTOK * 2 * 4);
    short* xb      = (short*)alloc((size_t)NTOK * D_MODEL * 2);
    short* w1t     = (short*)alloc((size_t)NE * D_HID * D_MODEL * 2);
    short* w2t     = (short*)alloc((size_t)NE * D_MODEL * D_HID * 2);
    short* hbuf    = (short*)alloc((size_t)NSLOT * D_HID * 2);
    float* ybuf    = (float*)alloc((size_t)NSLOT * D_MODEL * 4);

    hipMemsetAsync(meta, 0, 256, stream);
    k_cvt_x<<<dim3(NTOK * D_MODEL / (4 * 256)), 256, 0, stream>>>(x, xb);
    k_transpose_cvt2<<<dim3(64, 16, 16), 256, 0, stream>>>(w1, w2, w1t, w2t);
    k_router<<<dim3(NTOK), 64, 0, stream>>>(x, gw, tki, tkw);
    k_count<<<dim3(NTOK / 256), 256, 0, stream>>>(tki, cnt);
    k_scan<<<dim3(1), 64, 0, stream>>>(cnt, offs);
    k_fill<<<dim3(NTOK / 256), 256, 0, stream>>>(tki, tkw, offs, fill, list, wl, slot_of);
    k_gemm1<<<dim3(2048), 512, 0, stream>>>(xb, w1t, b1, offs, list, hbuf);
    k_gemm2<<<dim3(1024), 512, 0, stream>>>(hbuf, w2t, b2, offs, wl, ybuf);
    k_combine<<<dim3(NTOK), 256, 0, stream>>>(ybuf, slot_of, out);
}

// Round 11
// 423.486 us; speedup vs baseline: 1.1015x; 1.0857x over previous
//
#include <hip/hip_runtime.h>
#include <hip/hip_bf16.h>
#include <math.h>

#define D_MODEL 1024
#define D_HID   4096
#define NE      8
#define NTOK    4096
#define NSLOT   8192

typedef __attribute__((ext_vector_type(8))) short s8v;
typedef __attribute__((ext_vector_type(4))) float f32x4;

__device__ __forceinline__ short f2bf(float f) {
    unsigned u = __float_as_uint(f);
    unsigned r = (u + 0x7fffu + ((u >> 16) & 1u)) >> 16;
    return (short)r;
}

__device__ __forceinline__ void load_lds16(const short* g, short* l) {
    __builtin_amdgcn_global_load_lds(
        (const __attribute__((address_space(1))) void*)g,
        (__attribute__((address_space(3))) void*)l, 16, 0, 0);
}

// tanh-GELU (Hendrycks approx, max abs err ~3e-4 vs exact — far under the
// 0.031 bf16 floor we already carry). 0.5*(1+tanh(u)) == sigmoid(2u).
__device__ __forceinline__ float gelu_t(float v) {
    float u = v * fmaf(0.0356774081f, v * v, 0.7978845608f);
    float e = __expf(-2.0f * u);
    return v * __builtin_amdgcn_rcpf(1.0f + e);
}

// ---------------- fused x-convert + router ----------------
// one block per token row: convert 1024 fp32 -> bf16 AND compute top-2 gate.

__global__ void k_cvt_router(const float* __restrict__ x, const float* __restrict__ gw,
                             short* __restrict__ xb,
                             int* __restrict__ tki, float* __restrict__ tkw) {
    int n = blockIdx.x;
    int lane = threadIdx.x;
    const float4* x4 = (const float4*)x;
    const float4* g4 = (const float4*)gw;
    float4 xv[4];
    #pragma unroll
    for (int j = 0; j < 4; j++) xv[j] = x4[(size_t)n * 256 + lane + 64 * j];
    // bf16 write
    #pragma unroll
    for (int j = 0; j < 4; j++) {
        short4 o;
        o.x = f2bf(xv[j].x); o.y = f2bf(xv[j].y);
        o.z = f2bf(xv[j].z); o.w = f2bf(xv[j].w);
        *(short4*)(xb + (size_t)n * D_MODEL + 4 * (lane + 64 * j)) = o;
    }
    // router logits
    float l[8];
    #pragma unroll
    for (int e = 0; e < 8; e++) {
        float a = 0.f;
        #pragma unroll
        for (int j = 0; j < 4; j++) {
            float4 g = g4[e * 256 + lane + 64 * j];
            a = fmaf(xv[j].x, g.x, a);
            a = fmaf(xv[j].y, g.y, a);
            a = fmaf(xv[j].z, g.z, a);
            a = fmaf(xv[j].w, g.w, a);
        }
        #pragma unroll
        for (int s = 32; s > 0; s >>= 1) a += __shfl_xor(a, s);
        l[e] = a;
    }
    if (lane == 0) {
        float bv = -1e30f, sv = -1e30f; int bi = 0, si = 0;
        #pragma unroll
        for (int e = 0; e < 8; e++) {
            float v = l[e];
            if (v > bv) { sv = bv; si = bi; bv = v; bi = e; }
            else if (v > sv) { sv = v; si = e; }
        }
        float w0 = 1.f / (1.f + expf(sv - bv));
        tki[n * 2] = bi; tki[n * 2 + 1] = si;
        tkw[n * 2] = w0; tkw[n * 2 + 1] = 1.f - w0;
    }
}

// ---------------- weight transposes (merged) ----------------

__global__ void k_transpose_cvt2(const float* __restrict__ w1, const float* __restrict__ w2,
                                 short* __restrict__ w1t, short* __restrict__ w2t) {
    __shared__ float tile[64][65];
    int z = blockIdx.z;
    int R, C;
    const float* inp;
    short* outp;
    int tIdx = blockIdx.y * 64 + blockIdx.x;
    if (z < 8) {
        R = D_MODEL; C = D_HID;
        inp  = w1  + (size_t)z * R * C;
        outp = w1t + (size_t)z * R * C;
    } else {
        R = D_HID; C = D_MODEL;
        inp  = w2  + (size_t)(z - 8) * R * C;
        outp = w2t + (size_t)(z - 8) * R * C;
    }
    int tilesC = C >> 6;
    int c0 = (tIdx % tilesC) * 64;
    int r0 = (tIdx / tilesC) * 64;
    int t = threadIdx.x;
    #pragma unroll
    for (int p = 0; p < 4; p++) {
        int idx = p * 256 + t;
        int r = idx >> 4;
        int c4 = (idx & 15) * 4;
        float4 v = *(const float4*)(inp + (size_t)(r0 + r) * C + c0 + c4);
        tile[r][c4 + 0] = v.x; tile[r][c4 + 1] = v.y;
        tile[r][c4 + 2] = v.z; tile[r][c4 + 3] = v.w;
    }
    __syncthreads();
    #pragma unroll
    for (int p = 0; p < 4; p++) {
        int idx = p * 256 + t;
        int cc = idx >> 4;
        int rg = (idx & 15) * 4;
        short4 v;
        v.x = f2bf(tile[rg + 0][cc]);
        v.y = f2bf(tile[rg + 1][cc]);
        v.z = f2bf(tile[rg + 2][cc]);
        v.w = f2bf(tile[rg + 3][cc]);
        *(short4*)(outp + (size_t)(c0 + cc) * R + r0 + rg) = v;
    }
}

// ---------------- bucketing ----------------

__global__ void k_count(const int* __restrict__ tki, int* __restrict__ cnt) {
    int n = blockIdx.x * blockDim.x + threadIdx.x;
    if (n < NTOK) {
        atomicAdd(&cnt[tki[n * 2]], 1);
        atomicAdd(&cnt[tki[n * 2 + 1]], 1);
    }
}

__global__ void k_scan(const int* __restrict__ cnt, int* __restrict__ offs) {
    if (threadIdx.x == 0) {
        int a = 0;
        for (int e = 0; e < NE; e++) { offs[e] = a; a += cnt[e]; }
        offs[NE] = a;
    }
}

__global__ void k_fill(const int* __restrict__ tki, const float* __restrict__ tkw,
                       const int* __restrict__ offs, int* __restrict__ fill,
                       int* __restrict__ list, float* __restrict__ wl,
                       int* __restrict__ slot_of) {
    int n = blockIdx.x * blockDim.x + threadIdx.x;
    if (n < NTOK) {
        #pragma unroll
        for (int k = 0; k < 2; k++) {
            int e = tki[n * 2 + k];
            int p = offs[e] + atomicAdd(&fill[e], 1);
            list[p] = n;
            wl[p] = tkw[n * 2 + k];
            slot_of[n * 2 + k] = p;
        }
    }
}

// ---------------- GEMM 1 machinery (round-6 EXACT: 128x128, 2-buf counted) ----------------

#define STAGE_PAIR(ABASE, BBASE) \
    { _Pragma("unroll") \
      for (int c = 0; c < 4; c++) { \
          load_lds16(aS[c], (ABASE) + ldsD[c]); \
          load_lds16(bS[c], (BBASE) + ldsD[c]); \
          aS[c] += 64; bS[c] += 64; \
      } }

#define COMPUTE_STEP(ABASE, BBASE) \
    { _Pragma("unroll") \
      for (int kk2 = 0; kk2 < 2; kk2++) { \
          s8v a[4], b[4]; \
          _Pragma("unroll") \
          for (int i = 0; i < 4; i++) { \
              a[i] = *(const s8v*)((ABASE) + aO[i][kk2]); \
              b[i] = *(const s8v*)((BBASE) + bO[i][kk2]); \
          } \
          _Pragma("unroll") \
          for (int i = 0; i < 4; i++) \
              _Pragma("unroll") \
              for (int j = 0; j < 4; j++) \
                  acc[i][j] = __builtin_amdgcn_mfma_f32_16x16x32_bf16(a[i], b[j], acc[i][j], 0, 0, 0); \
      } }

#define PIPE_WAIT8 \
    asm volatile("s_waitcnt vmcnt(8)" ::: "memory"); \
    __builtin_amdgcn_s_barrier(); \
    __builtin_amdgcn_sched_barrier(0);

#define PIPE_WAIT0 \
    asm volatile("s_waitcnt vmcnt(0)" ::: "memory"); \
    __builtin_amdgcn_s_barrier(); \
    __builtin_amdgcn_sched_barrier(0);

#define PIPE_POST \
    asm volatile("" ::: "memory"); \
    __builtin_amdgcn_s_barrier();

#define GEMM_PIPE_LOOP(KDIM) \
    STAGE_PAIR(As0, Bs0); \
    for (int k0 = 0; k0 < (KDIM) - 128; k0 += 128) { \
        STAGE_PAIR(As1, Bs1); PIPE_WAIT8 COMPUTE_STEP(As0, Bs0) PIPE_POST \
        STAGE_PAIR(As0, Bs0); PIPE_WAIT8 COMPUTE_STEP(As1, Bs1) PIPE_POST \
    } \
    STAGE_PAIR(As1, Bs1); PIPE_WAIT8 COMPUTE_STEP(As0, Bs0) PIPE_POST \
    PIPE_WAIT0 COMPUTE_STEP(As1, Bs1)

#define GEMM_FRAG_SETUP \
    int tid = threadIdx.x; \
    int lane = tid & 63; \
    int wid = tid >> 6; \
    int wm = wid >> 1, wn = wid & 1; \
    f32x4 acc[4][4] = {}; \
    int ldsD[4]; \
    _Pragma("unroll") \
    for (int c = 0; c < 4; c++) ldsD[c] = (c * 256 + tid) * 8; \
    int aO[4][2], bO[4][2]; \
    _Pragma("unroll") \
    for (int i = 0; i < 4; i++) \
        _Pragma("unroll") \
        for (int k = 0; k < 2; k++) { \
            int l = k * 4 + (lane >> 4); \
            int R = wm * 64 + i * 16 + (lane & 15); \
            aO[i][k] = R * 64 + ((l ^ (R & 7)) * 8); \
            R = wn * 64 + i * 16 + (lane & 15); \
            bO[i][k] = R * 64 + ((l ^ (R & 7)) * 8); \
        }

// GEMM 1: round-6 exact (grid 8192, expert-per-XCD map), tanh-gelu epilogue.
__global__ __launch_bounds__(256, 2) void k_gemm1(
    const short* __restrict__ xb,      // [NTOK][D_MODEL] bf16
    const short* __restrict__ w1t,     // [E][D_HID][D_MODEL] bf16
    const float* __restrict__ b1,
    const int* __restrict__ offs,
    const int* __restrict__ list,
    short* __restrict__ hbuf)          // [NSLOT][D_HID] bf16
{
    int id = blockIdx.x;
    int w = (id & 7) * 1024 + (id >> 3);
    int e = w >> 10;
    int o0 = offs[e];
    int nE = offs[e + 1] - o0;
    int m0 = ((w >> 5) & 31) * 128;
    if (m0 >= nE) return;
    int n0 = (w & 31) * 128;

    __shared__ short As0[128 * 64], Bs0[128 * 64];
    __shared__ short As1[128 * 64], Bs1[128 * 64];

    GEMM_FRAG_SETUP

    const short* aS[4]; const short* bS[4];
    #pragma unroll
    for (int c = 0; c < 4; c++) {
        int i = c * 256 + tid;
        int rowT = i >> 3, s = i & 7;
        int ch = s ^ (rowT & 7);                 // pre-swizzled source chunk
        int r = m0 + rowT; if (r > nE - 1) r = nE - 1;
        int tok = list[o0 + r];
        aS[c] = xb + (size_t)tok * D_MODEL + ch * 8;
        bS[c] = w1t + ((size_t)e * D_HID + n0 + rowT) * D_MODEL + ch * 8;
    }

    GEMM_PIPE_LOOP(D_MODEL)

    int rBase = m0 + wm * 64 + (lane >> 4) * 4;
    int cBase = n0 + wn * 64 + (lane & 15);
    #pragma unroll
    for (int i = 0; i < 4; i++) {
        #pragma unroll
        for (int j = 0; j < 4; j++) {
            int cc = cBase + j * 16;
            float bias = b1[e * D_HID + cc];
            #pragma unroll
            for (int rg = 0; rg < 4; rg++) {
                int rr = rBase + i * 16 + rg;
                if (rr < nE) {
                    float v = acc[i][j][rg] + bias;
                    hbuf[(size_t)(o0 + rr) * D_HID + cc] = f2bf(gelu_t(v));
                }
            }
        }
    }
}

// ---------------- GEMM 2: 64(M)x128(N), single-buffer, TLP experiment ----------------
// m97-family single-buffer loop (round-3-verified in this codebase), 24 KB LDS
// -> 4-6 co-resident blocks/CU. 1024 useful blocks (4/CU). Round-6 map family:
// expert-per-XCD, 64 by-slots for full-skew coverage.

__global__ __launch_bounds__(256) void k_gemm2(
    const short* __restrict__ hbuf,    // [NSLOT][D_HID] bf16
    const short* __restrict__ w2t,     // [E][D_MODEL][D_HID] bf16
    const float* __restrict__ b2,
    const int* __restrict__ offs,
    const float* __restrict__ wl,
    float* __restrict__ ybuf)          // [NSLOT][D_MODEL] fp32
{
    int id = blockIdx.x;
    int w = (id & 7) * 512 + (id >> 3);
    int e = w >> 9;
    int o0 = offs[e];
    int nE = offs[e + 1] - o0;
    int m0 = ((w >> 3) & 63) * 64;
    if (m0 >= nE) return;
    int n0 = (w & 7) * 128;

    __shared__ short As[64 * 64];      // 8 KB
    __shared__ short Bs[128 * 64];     // 16 KB

    int tid = threadIdx.x;
    int lane = tid & 63;
    int wid = tid >> 6;
    int wm = wid >> 1, wn = wid & 1;   // 2x2 waves, wave tile 32(M) x 64(N)

    f32x4 acc[2][4] = {};

    const short* aS[2]; const short* bS[4];
    int ldsDa[2], ldsDb[4];
    #pragma unroll
    for (int c = 0; c < 2; c++) {
        int i = c * 256 + tid;                   // 0..511
        int rowT = i >> 3, s = i & 7;
        int ch = s ^ (rowT & 7);
        int r = m0 + rowT; if (r > nE - 1) r = nE - 1;
        aS[c] = hbuf + (size_t)(o0 + r) * D_HID + ch * 8;
        ldsDa[c] = i * 8;
    }
    #pragma unroll
    for (int c = 0; c < 4; c++) {
        int i = c * 256 + tid;                   // 0..1023
        int rowT = i >> 3, s = i & 7;
        int ch = s ^ (rowT & 7);
        bS[c] = w2t + ((size_t)e * D_MODEL + n0 + rowT) * D_HID + ch * 8;
        ldsDb[c] = i * 8;
    }

    int aO[2][2], bO[4][2];
    #pragma unroll
    for (int k = 0; k < 2; k++) {
        int l = k * 4 + (lane >> 4);
        #pragma unroll
        for (int i = 0; i < 2; i++) {
            int R = wm * 32 + i * 16 + (lane & 15);
            aO[i][k] = R * 64 + ((l ^ (R & 7)) * 8);
        }
        #pragma unroll
        for (int j = 0; j < 4; j++) {
            int R = wn * 64 + j * 16 + (lane & 15);
            bO[j][k] = R * 64 + ((l ^ (R & 7)) * 8);
        }
    }

    for (int k0 = 0; k0 < D_HID; k0 += 64) {
        __syncthreads();
        #pragma unroll
        for (int c = 0; c < 2; c++) { load_lds16(aS[c], As + ldsDa[c]); aS[c] += 64; }
        #pragma unroll
        for (int c = 0; c < 4; c++) { load_lds16(bS[c], Bs + ldsDb[c]); bS[c] += 64; }
        asm volatile("s_waitcnt vmcnt(0)" ::: "memory");
        __syncthreads();
        #pragma unroll
        for (int kk = 0; kk < 2; kk++) {
            s8v a[2], b[4];
            #pragma unroll
            for (int i = 0; i < 2; i++) a[i] = *(const s8v*)(As + aO[i][kk]);
            #pragma unroll
            for (int j = 0; j < 4; j++) b[j] = *(const s8v*)(Bs + bO[j][kk]);
            #pragma unroll
            for (int i = 0; i < 2; i++)
                #pragma unroll
                for (int j = 0; j < 4; j++)
                    acc[i][j] = __builtin_amdgcn_mfma_f32_16x16x32_bf16(a[i], b[j], acc[i][j], 0, 0, 0);
        }
    }

    int rBase = m0 + wm * 32 + (lane >> 4) * 4;
    int cBase = n0 + wn * 64 + (lane & 15);
    #pragma unroll
    for (int i = 0; i < 2; i++) {
        #pragma unroll
        for (int j = 0; j < 4; j++) {
            int cc = cBase + j * 16;
            float bias = b2[e * D_MODEL + cc];
            #pragma unroll
            for (int rg = 0; rg < 4; rg++) {
                int rr = rBase + i * 16 + rg;
                if (rr < nE) {
                    int slot = o0 + rr;
                    float wgt = wl[slot];
                    ybuf[(size_t)slot * D_MODEL + cc] = wgt * (acc[i][j][rg] + bias);
                }
            }
        }
    }
}

// ---------------- combine ----------------

__global__ void k_combine(const float* __restrict__ ybuf, const int* __restrict__ slot_of,
                          float* __restrict__ out) {
    int n = blockIdx.x;
    int s0 = slot_of[n * 2], s1 = slot_of[n * 2 + 1];
    int t = threadIdx.x;
    float4 a = *(const float4*)(ybuf + (size_t)s0 * D_MODEL + t * 4);
    float4 b = *(const float4*)(ybuf + (size_t)s1 * D_MODEL + t * 4);
    float4 o;
    o.x = a.x + b.x; o.y = a.y + b.y; o.z = a.z + b.z; o.w = a.w + b.w;
    *(float4*)(out + (size_t)n * D_MODEL + t * 4) = o;
}

// ---------------- launch ----------------

extern "C" void kernel_launch(void* const* d_in, const int* in_sizes, int n_in,
                              void* d_out, int out_size, void* d_ws, size_t ws_size,
                              hipStream_t stream) {
    const float* x  = (const float*)d_in[0];
    const float* gw = (const float*)d_in[1];
    const float* w1 = (const float*)d_in[2];
    const float* b1 = (const float*)d_in[3];
    const float* w2 = (const float*)d_in[4];
    const float* b2 = (const float*)d_in[5];
    float* out = (float*)d_out;

    char* ws = (char*)d_ws;
    size_t off = 0;
    auto alloc = [&](size_t bytes) -> void* {
        void* p = ws + off;
        off += (bytes + 255) & ~(size_t)255;
        return p;
    };
    int*   meta    = (int*)alloc(256);
    int*   cnt     = meta;
    int*   fill    = meta + 8;
    int*   offs    = meta + 16;
    int*   tki     = (int*)alloc((size_t)NTOK * 2 * 4);
    float* tkw     = (float*)alloc((size_t)NTOK * 2 * 4);
    int*   list    = (int*)alloc((size_t)NSLOT * 4);
    float* wl      = (float*)alloc((size_t)NSLOT * 4);
    int*   slot_of = (int*)alloc((size_t)NTOK * 2 * 4);
    short* xb      = (short*)alloc((size_t)NTOK * D_MODEL * 2);
    short* w1t     = (short*)alloc((size_t)NE * D_HID * D_MODEL * 2);
    short* w2t     = (short*)alloc((size_t)NE * D_MODEL * D_HID * 2);
    short* hbuf    = (short*)alloc((size_t)NSLOT * D_HID * 2);
    float* ybuf    = (float*)alloc((size_t)NSLOT * D_MODEL * 4);

    hipMemsetAsync(meta, 0, 256, stream);
    k_cvt_router<<<dim3(NTOK), 64, 0, stream>>>(x, gw, xb, tki, tkw);
    k_transpose_cvt2<<<dim3(64, 16, 16), 256, 0, stream>>>(w1, w2, w1t, w2t);
    k_count<<<dim3(NTOK / 256), 256, 0, stream>>>(tki, cnt);
    k_scan<<<dim3(1), 64, 0, stream>>>(cnt, offs);
    k_fill<<<dim3(NTOK / 256), 256, 0, stream>>>(tki, tkw, offs, fill, list, wl, slot_of);
    k_gemm1<<<dim3(8192), 256, 0, stream>>>(xb, w1t, b1, offs, list, hbuf);
    k_gemm2<<<dim3(4096), 256, 0, stream>>>(hbuf, w2t, b2, offs, wl, ybuf);
    k_combine<<<dim3(NTOK), 256, 0, stream>>>(ybuf, slot_of, out);
}